// Round 6
// baseline (25287.909 us; speedup 1.0000x reference)
//
#include <hip/hip_runtime.h>
#include <hip/hip_bf16.h>

#define T_STEPS 2048
#define HID 256
#define INF 72
#define OUTF 90
#define HSTR 528          // LDS h row stride (bytes)
#define HBUF (16 * HSTR)  // one h buffer = 8448 B

typedef __attribute__((ext_vector_type(4))) float f32x4;
typedef __attribute__((ext_vector_type(8))) short s16x8;

__device__ __forceinline__ unsigned short f2bf(float f) {
  union { float f; unsigned u; } v; v.f = f;
  unsigned r = (v.u + 0x7FFFu + ((v.u >> 16) & 1u)) >> 16;   // RNE
  return (unsigned short)r;
}
__device__ __forceinline__ float bf2f(unsigned short s) {
  union { unsigned u; float f; } v; v.u = ((unsigned)s) << 16;
  return v.f;
}
// raw v_exp2 + v_rcp gates: 2 trans + 2 VALU each (vs IEEE divide ~10 ops)
__device__ __forceinline__ float sigm(float x) {
  return __builtin_amdgcn_rcpf(1.f + __builtin_amdgcn_exp2f(-1.44269504f * x));
}
__device__ __forceinline__ float tanh_f(float x) {
  return 1.f - 2.f * __builtin_amdgcn_rcpf(1.f + __builtin_amdgcn_exp2f(2.88539008f * x));
}

// ---------------- input projection: h0 = relu(x @ W1^T + b1) ----------------
__global__ __launch_bounds__(256) void inproj(const float* __restrict__ x,
                                              const float* __restrict__ W1,
                                              const float* __restrict__ b1,
                                              float* __restrict__ h0) {
  __shared__ float w1s[HID][INF + 1];
  __shared__ float xs[16][INF];
  const int tid = threadIdx.x;
  const int r0 = blockIdx.x * 16;
  for (int i = tid; i < HID * INF; i += 256) w1s[i / INF][i % INF] = W1[i];
  for (int i = tid; i < 16 * INF; i += 256)
    xs[i / INF][i % INF] = x[(size_t)(r0 + i / INF) * INF + (i % INF)];
  __syncthreads();
  const float bj = b1[tid];
  for (int r = 0; r < 16; ++r) {
    float acc = bj;
#pragma unroll 8
    for (int k = 0; k < INF; ++k) acc += xs[r][k] * w1s[tid][k];
    h0[(size_t)(r0 + r) * HID + tid] = fmaxf(acc, 0.f);
  }
}

// ---------------- pack f32 -> bf16 ----------------
__global__ __launch_bounds__(256) void wpack(const float* __restrict__ w,
                                             unsigned short* __restrict__ o) {
  const size_t i = ((size_t)blockIdx.x * 256 + threadIdx.x) * 8;
  f32x4 a = *(const f32x4*)(w + i);
  f32x4 b = *(const f32x4*)(w + i + 4);
  s16x8 v;
#pragma unroll
  for (int e = 0; e < 4; ++e) { v[e] = (short)f2bf(a[e]); v[4 + e] = (short)f2bf(b[e]); }
  *(s16x8*)(o + i) = v;
}

// ------------- layer-1 gi GEMM (MFMA): one block per timestep t -------------
// gf1[t][sw16][lane][q01|q23] = h0[t] @ Wih1^T + bih1 + bhh1 (bf16 fragments)
__global__ __launch_bounds__(256) void gi_mfma(const float* __restrict__ h,
                                               const unsigned short* __restrict__ wb,
                                               const float* __restrict__ bih,
                                               const float* __restrict__ bhh,
                                               unsigned short* __restrict__ gi) {
  __shared__ __align__(16) char hs[16 * HSTR];
  __shared__ float bs[1024];
  const int tid = threadIdx.x;
  const int t = blockIdx.x;
  const int lane = tid & 63;
  const int wg = tid >> 6;
  const int j = lane & 15;
  const int hi = lane >> 4;
  for (int i = tid; i < 1024; i += 256) bs[i] = bih[i] + bhh[i];
  {
    const int row = tid >> 4;
    const int c0 = (tid & 15) * 16;
    const float* src = h + ((size_t)t * 16 + row) * 256 + c0;
    f32x4 v0 = *(const f32x4*)(src);
    f32x4 v1 = *(const f32x4*)(src + 4);
    f32x4 v2 = *(const f32x4*)(src + 8);
    f32x4 v3 = *(const f32x4*)(src + 12);
    s16x8 p0, p1;
#pragma unroll
    for (int e = 0; e < 4; ++e) {
      p0[e] = (short)f2bf(v0[e]); p0[4 + e] = (short)f2bf(v1[e]);
      p1[e] = (short)f2bf(v2[e]); p1[4 + e] = (short)f2bf(v3[e]);
    }
    *(s16x8*)(hs + row * HSTR + c0 * 2) = p0;
    *(s16x8*)(hs + row * HSTR + c0 * 2 + 16) = p1;
  }
  __syncthreads();
  const int hread = j * HSTR + hi * 16;
  f32x4 acc[4][4] = {};   // [ug2][q]
#pragma unroll
  for (int kt = 0; kt < 8; ++kt) {
    const int k = kt * 32 + hi * 8;
    const s16x8 a = *(const s16x8*)(hs + hread + kt * 64);
#pragma unroll
    for (int ug2 = 0; ug2 < 4; ++ug2)
#pragma unroll
      for (int q = 0; q < 4; ++q) {
        const s16x8 b = *(const s16x8*)(wb + (((size_t)(q << 8) + wg * 64 + ug2 * 16 + j) << 8) + k);
        acc[ug2][q] = __builtin_amdgcn_mfma_f32_16x16x32_bf16(a, b, acc[ug2][q], 0, 0, 0);
      }
  }
#pragma unroll
  for (int ug2 = 0; ug2 < 4; ++ug2) {
    const int sw = wg * 4 + ug2;
    const int u0 = wg * 64 + ug2 * 16 + j;
    s16x8 o0, o1;
#pragma unroll
    for (int r = 0; r < 4; ++r) {
      o0[r]     = (short)f2bf(acc[ug2][0][r] + bs[u0]);
      o0[4 + r] = (short)f2bf(acc[ug2][1][r] + bs[256 + u0]);
      o1[r]     = (short)f2bf(acc[ug2][2][r] + bs[512 + u0]);
      o1[4 + r] = (short)f2bf(acc[ug2][3][r] + bs[768 + u0]);
    }
    unsigned short* dst = gi + ((size_t)(t * 16 + sw) * 64 + lane) * 16;
    *(s16x8*)(dst) = o0;
    *(s16x8*)(dst + 8) = o1;
  }
}

// ================= fused pipeline: scan1 | gi2 | scan2 (3 blocks x 1024) =================

// ---- 16-wave LSTM scan: wave owns 16 units, ALL weights in 128 VGPRs ----
template <int ROLE>   // 0: layer1 (hb1 bf16 ys, releases cnt_rel); 1: layer2 (hout f32 ys, waits cnt_src)
__device__ __forceinline__ void scan_body(
    const unsigned short* __restrict__ gi,    // [T][16][64][16] bf16 fragment file
    const unsigned short* __restrict__ whbL,  // Whh bf16 [1024][256]
    const int* __restrict__ lengths,
    unsigned short* __restrict__ hb1,
    float* __restrict__ hout,
    unsigned int* cnt_rel, unsigned int* cnt_src,
    char* smem)
{
  const int tid  = threadIdx.x;
  const int lane = tid & 63;
  const int w    = tid >> 6;     // 0..15
  const int j    = lane & 15;
  const int hi   = lane >> 4;
  const int u    = w * 16 + j;

  s16x8 wfr[32];                 // all 4 gates x 8 k-tiles for this wave's 16 units
#pragma unroll
  for (int kt = 0; kt < 8; ++kt)
#pragma unroll
    for (int q = 0; q < 4; ++q)
      wfr[kt * 4 + q] =
          *(const s16x8*)(whbL + ((size_t)(q * 256 + u) << 8) + kt * 32 + hi * 8);

  for (int i = tid; i < 2 * HBUF / 4; i += 1024) ((float*)smem)[i] = 0.f;

  int len[4];
#pragma unroll
  for (int r = 0; r < 4; ++r) len[r] = lengths[hi * 4 + r];
  float c[4] = {};
  unsigned short hprev[4] = {};

  const unsigned short* gp = gi + ((size_t)w * 64 + lane) * 16;
  __syncthreads();

  unsigned cred = 0;
  if (ROLE == 1) {
    // BUGFIX (round 5): acquire credit BEFORE the initial gi[0] prefetch —
    // previously this load raced ahead of the gi2 producer and consumed poison.
    const unsigned t0 = (8 <= T_STEPS) ? 8u : (unsigned)T_STEPS;
    while (cred < t0) {
      cred = __hip_atomic_load(cnt_src, __ATOMIC_ACQUIRE, __HIP_MEMORY_SCOPE_AGENT);
      if (cred < t0) __builtin_amdgcn_s_sleep(2);
    }
  }

  s16x8 g0 = *(const s16x8*)(gp);        // gi[0]
  s16x8 g1 = *(const s16x8*)(gp + 8);
  const int hread = j * HSTR + hi * 16;

  for (int tg = 0; tg < T_STEPS; tg += 4) {
    if (ROLE == 1) {
      // deeper credit (tg+8) so the 1-step register prefetch never crosses unreleased data
      const unsigned target = (tg + 8 <= T_STEPS) ? (unsigned)(tg + 8) : (unsigned)T_STEPS;
      while (cred < target) {
        cred = __hip_atomic_load(cnt_src, __ATOMIC_ACQUIRE, __HIP_MEMORY_SCOPE_AGENT);
        if (cred < target) __builtin_amdgcn_s_sleep(2);
      }
    }
#pragma unroll
    for (int ts = 0; ts < 4; ++ts) {
      const int t = tg + ts;
      const char* hc = smem + (t & 1) * HBUF;
      char* hn = smem + ((t + 1) & 1) * HBUF;
      f32x4 acc[4];
#pragma unroll
      for (int r = 0; r < 4; ++r) {
        acc[0][r] = bf2f((unsigned short)g0[r]);
        acc[1][r] = bf2f((unsigned short)g0[4 + r]);
        acc[2][r] = bf2f((unsigned short)g1[r]);
        acc[3][r] = bf2f((unsigned short)g1[4 + r]);
      }
      {  // prefetch gi[t+1] into the just-freed registers
        const int tn = (t + 1 < T_STEPS) ? t + 1 : t;
        const unsigned short* gn = gp + (size_t)tn * 16384;
        g0 = *(const s16x8*)(gn);
        g1 = *(const s16x8*)(gn + 8);
      }
#pragma unroll
      for (int kt = 0; kt < 8; ++kt) {
        const s16x8 a = *(const s16x8*)(hc + hread + kt * 64);
#pragma unroll
        for (int q = 0; q < 4; ++q)
          acc[q] = __builtin_amdgcn_mfma_f32_16x16x32_bf16(a, wfr[kt * 4 + q], acc[q], 0, 0, 0);
      }
#pragma unroll
      for (int r = 0; r < 4; ++r) {
        const float i_  = sigm(acc[0][r]);
        const float f_  = sigm(acc[1][r]);
        const float tg_ = tanh_f(acc[2][r]);
        const float o_  = sigm(acc[3][r]);
        const float cn = f_ * c[r] + i_ * tg_;
        const float hv = o_ * tanh_f(cn);
        const bool m = t < len[r];
        c[r] = m ? cn : c[r];
        const unsigned short hb = m ? f2bf(hv) : hprev[r];
        hprev[r] = hb;
        const int b = hi * 4 + r;
        *(unsigned short*)(hn + b * HSTR + u * 2) = hb;
        if (ROLE == 0) hb1[(size_t)t * 4096 + b * 256 + u] = m ? hb : (unsigned short)0;
        else           hout[((size_t)t * 16 + b) * 256 + u] = m ? hv : 0.f;
      }
      if (ts == 3) {
        asm volatile("s_waitcnt vmcnt(0) lgkmcnt(0)" ::: "memory");
        __builtin_amdgcn_s_barrier();
        if (ROLE == 0 && tid == 0)
          __hip_atomic_store(cnt_rel, (unsigned)(t + 1), __ATOMIC_RELEASE, __HIP_MEMORY_SCOPE_AGENT);
      } else {
        asm volatile("s_waitcnt lgkmcnt(0)" ::: "memory");
        __builtin_amdgcn_s_barrier();
      }
      asm volatile("" ::: "memory");
    }
  }
}

// ---- gi2 producer: 16 waves, Wih2 slice fully in 128 VGPRs ----
__device__ __forceinline__ void gi2_body(
    const unsigned short* __restrict__ hb1,
    const unsigned short* __restrict__ wb2,
    const float* __restrict__ bih2, const float* __restrict__ bhh2,
    unsigned short* __restrict__ gf2,
    unsigned int* cnt_src, unsigned int* cnt_out)
{
  const int tid = threadIdx.x;
  const int lane = tid & 63;
  const int w = tid >> 6;
  const int j = lane & 15;
  const int hi = lane >> 4;
  const int u = w * 16 + j;

  s16x8 wfr[32];
  float bsum[4];
#pragma unroll
  for (int q = 0; q < 4; ++q) {
    const int col = q * 256 + u;
    bsum[q] = bih2[col] + bhh2[col];
#pragma unroll
    for (int kt = 0; kt < 8; ++kt)
      wfr[kt * 4 + q] = *(const s16x8*)(wb2 + ((size_t)col << 8) + kt * 32 + hi * 8);
  }

  unsigned cred = 0;
  for (int tg = 0; tg < T_STEPS; tg += 4) {
    while (cred < (unsigned)(tg + 4)) {
      cred = __hip_atomic_load(cnt_src, __ATOMIC_ACQUIRE, __HIP_MEMORY_SCOPE_AGENT);
      if (cred < (unsigned)(tg + 4)) __builtin_amdgcn_s_sleep(2);
    }
#pragma unroll
    for (int ts = 0; ts < 4; ++ts) {
      const int t = tg + ts;
      const unsigned short* ab = hb1 + (size_t)t * 4096 + j * 256 + hi * 8;
      f32x4 acc[4];
#pragma unroll
      for (int q = 0; q < 4; ++q)
#pragma unroll
        for (int r = 0; r < 4; ++r) acc[q][r] = bsum[q];
#pragma unroll
      for (int kt = 0; kt < 8; ++kt) {
        const s16x8 a = *(const s16x8*)(ab + kt * 32);
#pragma unroll
        for (int q = 0; q < 4; ++q)
          acc[q] = __builtin_amdgcn_mfma_f32_16x16x32_bf16(a, wfr[kt * 4 + q], acc[q], 0, 0, 0);
      }
      s16x8 o0, o1;
#pragma unroll
      for (int r = 0; r < 4; ++r) {
        o0[r]     = (short)f2bf(acc[0][r]);
        o0[4 + r] = (short)f2bf(acc[1][r]);
        o1[r]     = (short)f2bf(acc[2][r]);
        o1[4 + r] = (short)f2bf(acc[3][r]);
      }
      unsigned short* dst = gf2 + ((size_t)(t * 16 + w) * 64 + lane) * 16;
      *(s16x8*)(dst) = o0;
      *(s16x8*)(dst + 8) = o1;
    }
    asm volatile("s_waitcnt vmcnt(0)" ::: "memory");
    __builtin_amdgcn_s_barrier();
    if (tid == 0)
      __hip_atomic_store(cnt_out, (unsigned)(tg + 4), __ATOMIC_RELEASE, __HIP_MEMORY_SCOPE_AGENT);
    asm volatile("" ::: "memory");
  }
}

__global__ __launch_bounds__(1024, 1) void fused_pipe(
    const unsigned short* __restrict__ gf1,
    const unsigned short* __restrict__ whb,   // Whh bf16 [2][1024][256]
    const unsigned short* __restrict__ wb,    // Wih bf16 [2][1024][256]
    const float* __restrict__ bih, const float* __restrict__ bhh,
    const int* __restrict__ lengths,
    unsigned short* hb1, unsigned short* gf2, float* hout2,
    unsigned int* cnts)
{
  extern __shared__ char smem[];
  if (blockIdx.x == 0)
    scan_body<0>(gf1, whb, lengths, hb1, nullptr, cnts, nullptr, smem);
  else if (blockIdx.x == 1)
    gi2_body(hb1, wb + 262144, bih + 1024, bhh + 1024, gf2, cnts, cnts + 16);
  else
    scan_body<1>(gf2, whb + 262144, lengths, nullptr, hout2, nullptr, cnts + 16, smem);
}

// ---------------- output projection: y = mask ? h2 @ W2^T + b2 : 0 ----------------
__global__ __launch_bounds__(256) void outproj(const float* __restrict__ h2,
                                               const float* __restrict__ W2,
                                               const float* __restrict__ b2,
                                               const int* __restrict__ lengths,
                                               float* __restrict__ y) {
  __shared__ float w2s[OUTF][HID + 1];
  __shared__ float hs[8][HID + 1];
  const int tid = threadIdx.x;
  const int r0 = blockIdx.x * 8;
  for (int i = tid; i < OUTF * HID; i += 256) w2s[i / HID][i % HID] = W2[i];
  for (int i = tid; i < 8 * HID; i += 256)
    hs[i / HID][i % HID] = h2[(size_t)(r0 + i / HID) * HID + (i % HID)];
  __syncthreads();
  for (int oi = tid; oi < 8 * OUTF; oi += 256) {
    const int r = oi / OUTF, o = oi % OUTF;
    const int row = r0 + r, t = row >> 4, b = row & 15;
    float acc = b2[o];
#pragma unroll 8
    for (int k = 0; k < HID; ++k) acc += hs[r][k] * w2s[o][k];
    y[(size_t)row * OUTF + o] = (t < lengths[b]) ? acc : 0.f;
  }
}

extern "C" void kernel_launch(void* const* d_in, const int* in_sizes, int n_in,
                              void* d_out, int out_size, void* d_ws, size_t ws_size,
                              hipStream_t stream) {
  const float* x      = (const float*)d_in[0];
  const int*   lengths= (const int*)d_in[1];
  const float* W1     = (const float*)d_in[2];
  const float* b1     = (const float*)d_in[3];
  const float* Wih    = (const float*)d_in[4];
  const float* Whh    = (const float*)d_in[5];
  const float* bih    = (const float*)d_in[6];
  const float* bhh    = (const float*)d_in[7];
  const float* W2     = (const float*)d_in[8];
  const float* b2     = (const float*)d_in[9];
  float* out = (float*)d_out;

  char* ws = (char*)d_ws;
  float*          h0   = (float*)(ws);                          // 32 MB
  unsigned short* gf1  = (unsigned short*)(ws + 33554432);      // 64 MB
  unsigned short* hb1  = (unsigned short*)(ws + 100663296);     // 16 MB
  unsigned short* gf2  = (unsigned short*)(ws + 117440512);     // 64 MB
  float*          h2o  = (float*)(ws + 184549376);              // 32 MB
  unsigned short* wb   = (unsigned short*)(ws + 218103808);     // 1 MB (Wih bf16)
  unsigned short* whb  = (unsigned short*)(ws + 219152384);     // 1 MB (Whh bf16)
  unsigned int*   cnts = (unsigned int*)(ws + 220200960);       // 256 B

  wpack<<<256, 256, 0, stream>>>(Wih, wb);
  wpack<<<256, 256, 0, stream>>>(Whh, whb);
  inproj<<<2048, 256, 0, stream>>>(x, W1, b1, h0);
  gi_mfma<<<2048, 256, 0, stream>>>(h0, wb, bih, bhh, gf1);

  hipMemsetAsync((void*)cnts, 0, 256, stream);
  fused_pipe<<<3, 1024, 2 * HBUF, stream>>>(gf1, whb, wb, bih, bhh, lengths,
                                            hb1, gf2, h2o, cnts);

  outproj<<<4096, 256, 0, stream>>>(h2o, W2, b2, lengths, out);
}

// Round 7
// 10663.817 us; speedup vs baseline: 2.3714x; 2.3714x over previous
//
#include <hip/hip_runtime.h>
#include <hip/hip_bf16.h>

#define T_STEPS 2048
#define HID 256
#define INF 72
#define OUTF 90
#define HSTR 528          // LDS h row stride for gi_mfma (bytes)

typedef __attribute__((ext_vector_type(4))) float f32x4;
typedef __attribute__((ext_vector_type(8))) short s16x8;

__device__ __forceinline__ unsigned short f2bf(float f) {
  union { float f; unsigned u; } v; v.f = f;
  unsigned r = (v.u + 0x7FFFu + ((v.u >> 16) & 1u)) >> 16;   // RNE
  return (unsigned short)r;
}
__device__ __forceinline__ float bf2f(unsigned short s) {
  union { unsigned u; float f; } v; v.u = ((unsigned)s) << 16;
  return v.f;
}
__device__ __forceinline__ float sigm(float x) {
  return __builtin_amdgcn_rcpf(1.f + __builtin_amdgcn_exp2f(-1.44269504f * x));
}
__device__ __forceinline__ float tanh_f(float x) {
  return 1.f - 2.f * __builtin_amdgcn_rcpf(1.f + __builtin_amdgcn_exp2f(2.88539008f * x));
}

// ---------------- input projection: h0 = relu(x @ W1^T + b1) ----------------
__global__ __launch_bounds__(256) void inproj(const float* __restrict__ x,
                                              const float* __restrict__ W1,
                                              const float* __restrict__ b1,
                                              float* __restrict__ h0) {
  __shared__ float w1s[HID][INF + 1];
  __shared__ float xs[16][INF];
  const int tid = threadIdx.x;
  const int r0 = blockIdx.x * 16;
  for (int i = tid; i < HID * INF; i += 256) w1s[i / INF][i % INF] = W1[i];
  for (int i = tid; i < 16 * INF; i += 256)
    xs[i / INF][i % INF] = x[(size_t)(r0 + i / INF) * INF + (i % INF)];
  __syncthreads();
  const float bj = b1[tid];
  for (int r = 0; r < 16; ++r) {
    float acc = bj;
#pragma unroll 8
    for (int k = 0; k < INF; ++k) acc += xs[r][k] * w1s[tid][k];
    h0[(size_t)(r0 + r) * HID + tid] = fmaxf(acc, 0.f);
  }
}

// ---------------- pack f32 -> bf16 ----------------
__global__ __launch_bounds__(256) void wpack(const float* __restrict__ w,
                                             unsigned short* __restrict__ o) {
  const size_t i = ((size_t)blockIdx.x * 256 + threadIdx.x) * 8;
  f32x4 a = *(const f32x4*)(w + i);
  f32x4 b = *(const f32x4*)(w + i + 4);
  s16x8 v;
#pragma unroll
  for (int e = 0; e < 4; ++e) { v[e] = (short)f2bf(a[e]); v[4 + e] = (short)f2bf(b[e]); }
  *(s16x8*)(o + i) = v;
}

// ------------- layer-1 gi GEMM (MFMA): one block per timestep t -------------
// gf1[t][sw16][lane][16] = h0[t] @ Wih1^T + bih1 + bhh1 (bf16 fragments; sw*16+j = unit)
__global__ __launch_bounds__(256) void gi_mfma(const float* __restrict__ h,
                                               const unsigned short* __restrict__ wb,
                                               const float* __restrict__ bih,
                                               const float* __restrict__ bhh,
                                               unsigned short* __restrict__ gi) {
  __shared__ __align__(16) char hs[16 * HSTR];
  __shared__ float bs[1024];
  const int tid = threadIdx.x;
  const int t = blockIdx.x;
  const int lane = tid & 63;
  const int wg = tid >> 6;
  const int j = lane & 15;
  const int hi = lane >> 4;
  for (int i = tid; i < 1024; i += 256) bs[i] = bih[i] + bhh[i];
  {
    const int row = tid >> 4;
    const int c0 = (tid & 15) * 16;
    const float* src = h + ((size_t)t * 16 + row) * 256 + c0;
    f32x4 v0 = *(const f32x4*)(src);
    f32x4 v1 = *(const f32x4*)(src + 4);
    f32x4 v2 = *(const f32x4*)(src + 8);
    f32x4 v3 = *(const f32x4*)(src + 12);
    s16x8 p0, p1;
#pragma unroll
    for (int e = 0; e < 4; ++e) {
      p0[e] = (short)f2bf(v0[e]); p0[4 + e] = (short)f2bf(v1[e]);
      p1[e] = (short)f2bf(v2[e]); p1[4 + e] = (short)f2bf(v3[e]);
    }
    *(s16x8*)(hs + row * HSTR + c0 * 2) = p0;
    *(s16x8*)(hs + row * HSTR + c0 * 2 + 16) = p1;
  }
  __syncthreads();
  const int hread = j * HSTR + hi * 16;
  f32x4 acc[4][4] = {};   // [ug2][q]
#pragma unroll
  for (int kt = 0; kt < 8; ++kt) {
    const int k = kt * 32 + hi * 8;
    const s16x8 a = *(const s16x8*)(hs + hread + kt * 64);
#pragma unroll
    for (int ug2 = 0; ug2 < 4; ++ug2)
#pragma unroll
      for (int q = 0; q < 4; ++q) {
        const s16x8 b = *(const s16x8*)(wb + (((size_t)(q << 8) + wg * 64 + ug2 * 16 + j) << 8) + k);
        acc[ug2][q] = __builtin_amdgcn_mfma_f32_16x16x32_bf16(a, b, acc[ug2][q], 0, 0, 0);
      }
  }
#pragma unroll
  for (int ug2 = 0; ug2 < 4; ++ug2) {
    const int sw = wg * 4 + ug2;
    const int u0 = wg * 64 + ug2 * 16 + j;
    s16x8 o0, o1;
#pragma unroll
    for (int r = 0; r < 4; ++r) {
      o0[r]     = (short)f2bf(acc[ug2][0][r] + bs[u0]);
      o0[4 + r] = (short)f2bf(acc[ug2][1][r] + bs[256 + u0]);
      o1[r]     = (short)f2bf(acc[ug2][2][r] + bs[512 + u0]);
      o1[4 + r] = (short)f2bf(acc[ug2][3][r] + bs[768 + u0]);
    }
    unsigned short* dst = gi + ((size_t)(t * 16 + sw) * 64 + lane) * 16;
    *(s16x8*)(dst) = o0;
    *(s16x8*)(dst + 8) = o1;
  }
}

// ============ fused pipeline: scan1{0,8} | gi2{2,10} | scan2{1,9} (2 CUs each) ============

// ---- tensor-parallel LSTM scan half: this CU owns 128 units, ALL weights in regs ----
template <int ROLE>   // 0: layer1 (writes hb1 bf16 ys); 1: layer2 (writes hout f32 ys)
__device__ __forceinline__ void scan2cu(
    const unsigned short* __restrict__ gi,    // [T][16][64][16] bf16 fragment file
    const unsigned short* __restrict__ whbL,  // Whh bf16 [1024][256] (this layer)
    const int* __restrict__ lengths,
    unsigned short* __restrict__ hb1,
    float* __restrict__ hout,
    unsigned short* hx,                       // [4][16][256] bf16 exchange (4-slot)
    unsigned* myflag, unsigned* peerflag,
    unsigned* cntA, unsigned* cntB,           // ROLE1: gi2 half credits
    int half)
{
  const int tid  = threadIdx.x;
  const int lane = tid & 63;
  const int w    = tid >> 6;     // 0..7
  const int j    = lane & 15;
  const int hi   = lane >> 4;
  const int u    = half * 128 + w * 16 + j;

  s16x8 wfr[32];                 // 4 gates x 8 k-tiles for this wave's 16 units (128 VGPRs)
#pragma unroll
  for (int kt = 0; kt < 8; ++kt)
#pragma unroll
    for (int q = 0; q < 4; ++q)
      wfr[kt * 4 + q] =
          *(const s16x8*)(whbL + ((size_t)(q * 256 + u) << 8) + kt * 32 + hi * 8);

  int len[4];
#pragma unroll
  for (int r = 0; r < 4; ++r) len[r] = lengths[hi * 4 + r];
  float c[4] = {};
  unsigned short hprev[4] = {};

  // zero own half of hx slot 0 (h_0 = 0), then publish flag=1
  {
    unsigned* z = (unsigned*)hx;
    for (int i = tid; i < 1024; i += 512)
      z[(i >> 6) * 128 + half * 64 + (i & 63)] = 0u;
  }
  asm volatile("s_waitcnt vmcnt(0)" ::: "memory");
  __builtin_amdgcn_s_barrier();
  if (tid == 0) __hip_atomic_store(myflag, 1u, __ATOMIC_RELEASE, __HIP_MEMORY_SCOPE_AGENT);

  unsigned cred = 0;
  if (ROLE == 1) {   // initial credit BEFORE first gi touch (round-5 bugfix discipline)
    while (cred < 8u) {
      unsigned a = __hip_atomic_load(cntA, __ATOMIC_ACQUIRE, __HIP_MEMORY_SCOPE_AGENT);
      unsigned b = __hip_atomic_load(cntB, __ATOMIC_ACQUIRE, __HIP_MEMORY_SCOPE_AGENT);
      cred = a < b ? a : b;
      if (cred < 8u) __builtin_amdgcn_s_sleep(2);
    }
  }
  const unsigned short* gp = gi + ((size_t)(half * 8 + w) * 64 + lane) * 16;
  s16x8 gE0 = *(const s16x8*)(gp);            // gi[0]
  s16x8 gE1 = *(const s16x8*)(gp + 8);
  s16x8 gO0 = *(const s16x8*)(gp + 16384);    // gi[1]
  s16x8 gO1 = *(const s16x8*)(gp + 16384 + 8);

  for (int tg = 0; tg < T_STEPS; tg += 4) {
    if (ROLE == 1) {
      const unsigned target = (tg + 8 <= T_STEPS) ? (unsigned)(tg + 8) : (unsigned)T_STEPS;
      while (cred < target) {
        unsigned a = __hip_atomic_load(cntA, __ATOMIC_ACQUIRE, __HIP_MEMORY_SCOPE_AGENT);
        unsigned b = __hip_atomic_load(cntB, __ATOMIC_ACQUIRE, __HIP_MEMORY_SCOPE_AGENT);
        cred = a < b ? a : b;
        if (cred < target) __builtin_amdgcn_s_sleep(2);
      }
    }
#pragma unroll
    for (int ts = 0; ts < 4; ++ts) {
      const int t = tg + ts;
      s16x8& g0 = (ts & 1) ? gO0 : gE0;       // compile-time select (static indexing)
      s16x8& g1 = (ts & 1) ? gO1 : gE1;

      // wait for peer's h_t publication
      while (__hip_atomic_load(peerflag, __ATOMIC_ACQUIRE, __HIP_MEMORY_SCOPE_AGENT) < (unsigned)(t + 1))
        __builtin_amdgcn_s_sleep(1);

      // A-fragments straight from the exchange buffer (XCD-local L2)
      const unsigned short* hsrc = hx + (size_t)(t & 3) * 4096 + j * 256 + hi * 8;
      s16x8 av[8];
#pragma unroll
      for (int kt = 0; kt < 8; ++kt) av[kt] = *(const s16x8*)(hsrc + kt * 32);

      f32x4 acc[4];
#pragma unroll
      for (int r = 0; r < 4; ++r) {
        acc[0][r] = bf2f((unsigned short)g0[r]);
        acc[1][r] = bf2f((unsigned short)g0[4 + r]);
        acc[2][r] = bf2f((unsigned short)g1[r]);
        acc[3][r] = bf2f((unsigned short)g1[4 + r]);
      }
      {  // 2-step-deep gi prefetch into the just-freed register set
        const int tn = (t + 2 < T_STEPS) ? t + 2 : T_STEPS - 1;
        const unsigned short* gn = gp + (size_t)tn * 16384;
        g0 = *(const s16x8*)(gn);
        g1 = *(const s16x8*)(gn + 8);
      }
#pragma unroll
      for (int kt = 0; kt < 8; ++kt)
#pragma unroll
        for (int q = 0; q < 4; ++q)
          acc[q] = __builtin_amdgcn_mfma_f32_16x16x32_bf16(av[kt], wfr[kt * 4 + q], acc[q], 0, 0, 0);

      unsigned short* hdst = hx + (size_t)((t + 1) & 3) * 4096;
#pragma unroll
      for (int r = 0; r < 4; ++r) {
        const float i_  = sigm(acc[0][r]);
        const float f_  = sigm(acc[1][r]);
        const float tg_ = tanh_f(acc[2][r]);
        const float o_  = sigm(acc[3][r]);
        const float cn = f_ * c[r] + i_ * tg_;
        const float hv = o_ * tanh_f(cn);
        const bool m = t < len[r];
        c[r] = m ? cn : c[r];
        const unsigned short hb = m ? f2bf(hv) : hprev[r];
        hprev[r] = hb;
        const int b = hi * 4 + r;
        hdst[b * 256 + u] = hb;
        if (ROLE == 0) hb1[(size_t)t * 4096 + b * 256 + u] = m ? hb : (unsigned short)0;
        else           hout[((size_t)t * 16 + b) * 256 + u] = m ? hv : 0.f;
      }
      // publish h_{t+1}: drain all waves' stores, then one release flag
      asm volatile("s_waitcnt vmcnt(0)" ::: "memory");
      __builtin_amdgcn_s_barrier();
      if (tid == 0)
        __hip_atomic_store(myflag, (unsigned)(t + 2), __ATOMIC_RELEASE, __HIP_MEMORY_SCOPE_AGENT);
      asm volatile("" ::: "memory");
    }
  }
}

// ---- gi2 producer half: gates qbase..qbase+1 for all 256 units, weights in regs ----
__device__ __forceinline__ void gi2b(int qbase,
    const unsigned short* __restrict__ hb1,
    const unsigned short* __restrict__ wb2,
    const float* __restrict__ bih2, const float* __restrict__ bhh2,
    unsigned short* __restrict__ gf2,
    unsigned* f1a, unsigned* f1b, unsigned* cnt_out)
{
  const int tid = threadIdx.x;
  const int lane = tid & 63;
  const int w = tid >> 6;
  const int j = lane & 15;
  const int hi = lane >> 4;

  s16x8 wfr[2][2][8];   // [qh][ug][kt] = 32 tiles = 128 VGPRs
  float bsum[2][2];
#pragma unroll
  for (int qh = 0; qh < 2; ++qh)
#pragma unroll
    for (int ug = 0; ug < 2; ++ug) {
      const int col = (qbase + qh) * 256 + w * 32 + ug * 16 + j;
      bsum[qh][ug] = bih2[col] + bhh2[col];
#pragma unroll
      for (int kt = 0; kt < 8; ++kt)
        wfr[qh][ug][kt] = *(const s16x8*)(wb2 + ((size_t)col << 8) + kt * 32 + hi * 8);
    }

  const int qoff = qbase * 4;   // 0 or 8 shorts within the 16-short lane record
  unsigned cred = 0;
  for (int tg = 0; tg < T_STEPS; tg += 4) {
    const unsigned target = (unsigned)(tg + 5);   // hb1[tg+3] needs flag >= tg+5
    while (cred < target) {
      unsigned a = __hip_atomic_load(f1a, __ATOMIC_ACQUIRE, __HIP_MEMORY_SCOPE_AGENT);
      unsigned b = __hip_atomic_load(f1b, __ATOMIC_ACQUIRE, __HIP_MEMORY_SCOPE_AGENT);
      cred = a < b ? a : b;
      if (cred < target) __builtin_amdgcn_s_sleep(2);
    }
#pragma unroll
    for (int ts = 0; ts < 4; ++ts) {
      const int t = tg + ts;
      const unsigned short* ab = hb1 + (size_t)t * 4096 + j * 256 + hi * 8;
      f32x4 acc[2][2];
#pragma unroll
      for (int qh = 0; qh < 2; ++qh)
#pragma unroll
        for (int ug = 0; ug < 2; ++ug)
#pragma unroll
          for (int r = 0; r < 4; ++r) acc[qh][ug][r] = bsum[qh][ug];
#pragma unroll
      for (int kt = 0; kt < 8; ++kt) {
        const s16x8 a = *(const s16x8*)(ab + kt * 32);
#pragma unroll
        for (int qh = 0; qh < 2; ++qh)
#pragma unroll
          for (int ug = 0; ug < 2; ++ug)
            acc[qh][ug] = __builtin_amdgcn_mfma_f32_16x16x32_bf16(a, wfr[qh][ug][kt], acc[qh][ug], 0, 0, 0);
      }
#pragma unroll
      for (int ug = 0; ug < 2; ++ug) {
        s16x8 o;
#pragma unroll
        for (int r = 0; r < 4; ++r) {
          o[r]     = (short)f2bf(acc[0][ug][r]);
          o[4 + r] = (short)f2bf(acc[1][ug][r]);
        }
        *(s16x8*)(gf2 + ((size_t)(t * 16 + w * 2 + ug) * 64 + lane) * 16 + qoff) = o;
      }
    }
    asm volatile("s_waitcnt vmcnt(0)" ::: "memory");
    __builtin_amdgcn_s_barrier();
    if (tid == 0)
      __hip_atomic_store(cnt_out, (unsigned)(tg + 4), __ATOMIC_RELEASE, __HIP_MEMORY_SCOPE_AGENT);
    asm volatile("" ::: "memory");
  }
}

__global__ __launch_bounds__(512, 2) void fused_pipe(
    const unsigned short* __restrict__ gf1,
    const unsigned short* __restrict__ whb,   // Whh bf16 [2][1024][256]
    const unsigned short* __restrict__ wb,    // Wih bf16 [2][1024][256]
    const float* __restrict__ bih, const float* __restrict__ bhh,
    const int* __restrict__ lengths,
    unsigned short* hb1, unsigned short* gf2, float* hout2,
    unsigned short* hx1, unsigned short* hx2, unsigned* sync)
{
  // bid%8 targets the XCD under round-robin dispatch (perf heuristic only):
  // {0,8}=scan1 pair, {1,9}=scan2 pair, {2,10}=gi2 pair
  const int bid = blockIdx.x;
  if (bid == 0)
    scan2cu<0>(gf1, whb, lengths, hb1, nullptr, hx1, sync + 0, sync + 32, nullptr, nullptr, 0);
  else if (bid == 8)
    scan2cu<0>(gf1, whb, lengths, hb1, nullptr, hx1, sync + 32, sync + 0, nullptr, nullptr, 1);
  else if (bid == 1)
    scan2cu<1>(gf2, whb + 262144, lengths, nullptr, hout2, hx2, sync + 64, sync + 96, sync + 128, sync + 160, 0);
  else if (bid == 9)
    scan2cu<1>(gf2, whb + 262144, lengths, nullptr, hout2, hx2, sync + 96, sync + 64, sync + 128, sync + 160, 1);
  else if (bid == 2)
    gi2b(0, hb1, wb + 262144, bih + 1024, bhh + 1024, gf2, sync + 0, sync + 32, sync + 128);
  else if (bid == 10)
    gi2b(2, hb1, wb + 262144, bih + 1024, bhh + 1024, gf2, sync + 0, sync + 32, sync + 160);
}

// ---------------- output projection: y = mask ? h2 @ W2^T + b2 : 0 ----------------
__global__ __launch_bounds__(256) void outproj(const float* __restrict__ h2,
                                               const float* __restrict__ W2,
                                               const float* __restrict__ b2,
                                               const int* __restrict__ lengths,
                                               float* __restrict__ y) {
  __shared__ float w2s[OUTF][HID + 1];
  __shared__ float hs[8][HID + 1];
  const int tid = threadIdx.x;
  const int r0 = blockIdx.x * 8;
  for (int i = tid; i < OUTF * HID; i += 256) w2s[i / HID][i % HID] = W2[i];
  for (int i = tid; i < 8 * HID; i += 256)
    hs[i / HID][i % HID] = h2[(size_t)(r0 + i / HID) * HID + (i % HID)];
  __syncthreads();
  for (int oi = tid; oi < 8 * OUTF; oi += 256) {
    const int r = oi / OUTF, o = oi % OUTF;
    const int row = r0 + r, t = row >> 4, b = row & 15;
    float acc = b2[o];
#pragma unroll 8
    for (int k = 0; k < HID; ++k) acc += hs[r][k] * w2s[o][k];
    y[(size_t)row * OUTF + o] = (t < lengths[b]) ? acc : 0.f;
  }
}

extern "C" void kernel_launch(void* const* d_in, const int* in_sizes, int n_in,
                              void* d_out, int out_size, void* d_ws, size_t ws_size,
                              hipStream_t stream) {
  const float* x      = (const float*)d_in[0];
  const int*   lengths= (const int*)d_in[1];
  const float* W1     = (const float*)d_in[2];
  const float* b1     = (const float*)d_in[3];
  const float* Wih    = (const float*)d_in[4];
  const float* Whh    = (const float*)d_in[5];
  const float* bih    = (const float*)d_in[6];
  const float* bhh    = (const float*)d_in[7];
  const float* W2     = (const float*)d_in[8];
  const float* b2     = (const float*)d_in[9];
  float* out = (float*)d_out;

  char* ws = (char*)d_ws;
  float*          h0   = (float*)(ws);                          // 32 MB
  unsigned short* gf1  = (unsigned short*)(ws + 33554432);      // 64 MB
  unsigned short* hb1  = (unsigned short*)(ws + 100663296);     // 16 MB
  unsigned short* gf2  = (unsigned short*)(ws + 117440512);     // 64 MB
  float*          h2o  = (float*)(ws + 184549376);              // 32 MB
  unsigned short* wb   = (unsigned short*)(ws + 218103808);     // 1 MB (Wih bf16)
  unsigned short* whb  = (unsigned short*)(ws + 219152384);     // 1 MB (Whh bf16)
  unsigned short* hx1  = (unsigned short*)(ws + 220200960);     // 32 KB exchange L1
  unsigned short* hx2  = (unsigned short*)(ws + 220233728);     // 32 KB exchange L2
  unsigned*       sync = (unsigned*)(ws + 220266496);           // 768 B flags/credits

  wpack<<<256, 256, 0, stream>>>(Wih, wb);
  wpack<<<256, 256, 0, stream>>>(Whh, whb);
  inproj<<<2048, 256, 0, stream>>>(x, W1, b1, h0);
  gi_mfma<<<2048, 256, 0, stream>>>(h0, wb, bih, bhh, gf1);

  hipMemsetAsync((void*)sync, 0, 768, stream);
  fused_pipe<<<11, 512, 0, stream>>>(gf1, whb, wb, bih, bhh, lengths,
                                     hb1, gf2, h2o, hx1, hx2, sync);

  outproj<<<4096, 256, 0, stream>>>(h2o, W2, b2, lengths, out);
}